// Round 2
// baseline (21.016 us; speedup 1.0000x reference)
//
#include <hip/hip_runtime.h>
#include <math.h>

#define B_SZ  32
#define T_LEN 500
#define VOCAB 8192

// Kernel A: cross[i][j] = sum_t clip(x[j, t, Y[i, t]], -30, 30)
// One block per (i, j) pair; 256 threads gather + block-reduce.
__global__ __launch_bounds__(256)
void infonce_cross_kernel(const float* __restrict__ x,
                          const int*   __restrict__ Y,
                          float*       __restrict__ cross) {
    const int j = blockIdx.x;   // which sample's logits
    const int i = blockIdx.y;   // which sample's targets
    const float* __restrict__ xj = x + (size_t)j * T_LEN * VOCAB;
    const int*   __restrict__ Yi = Y + i * T_LEN;

    float acc = 0.0f;
    for (int t = threadIdx.x; t < T_LEN; t += 256) {
        const int y = Yi[t];                       // L2-resident after first i-row
        float v = xj[(size_t)t * VOCAB + y];       // scattered gather
        v = fminf(fmaxf(v, -30.0f), 30.0f);
        acc += v;
    }

    // wave (64-lane) butterfly reduce
    #pragma unroll
    for (int off = 32; off > 0; off >>= 1)
        acc += __shfl_down(acc, off, 64);

    __shared__ float ws[4];
    const int lane = threadIdx.x & 63;
    const int wid  = threadIdx.x >> 6;
    if (lane == 0) ws[wid] = acc;
    __syncthreads();
    if (threadIdx.x == 0) {
        cross[i * B_SZ + j] = ws[0] + ws[1] + ws[2] + ws[3];
    }
}

// Kernel B: per-row logsumexp + logaddexp(B_buf[0]) + final scalars.
// Single block, single wave; lanes 0..31 own one row each.
__global__ __launch_bounds__(64)
void infonce_finalize_kernel(const float* __restrict__ cross,
                             const float* __restrict__ B_buf,
                             float*       __restrict__ out) {
    __shared__ double lt[B_SZ];
    const int i = threadIdx.x;

    if (i < B_SZ) {
        // rowmax
        double m = -INFINITY;
        #pragma unroll
        for (int jj = 0; jj < B_SZ; ++jj) {
            double c = (double)cross[i * B_SZ + jj];
            m = fmax(m, c);
        }
        // exp-sum
        double s = 0.0;
        #pragma unroll
        for (int jj = 0; jj < B_SZ; ++jj) {
            s += exp((double)cross[i * B_SZ + jj] - m);
        }
        const double lse = m + log(s);
        // logaddexp with B_buf[0]
        const double b0 = (double)B_buf[0];
        const double hi = fmax(lse, b0);
        const double lo = fmin(lse, b0);
        const double den = hi + log1p(exp(lo - hi));
        const double num = (double)cross[i * B_SZ + i];
        lt[i] = num - den;
    }
    __syncthreads();

    if (i == 0) {
        double sum_lt = 0.0, sum_exp = 0.0;
        #pragma unroll
        for (int k = 0; k < B_SZ; ++k) {
            sum_lt  += lt[k];
            sum_exp += exp(lt[k]);
        }
        out[0] = (float)(-sum_lt / ((double)B_SZ * (double)T_LEN)); // loss
        out[1] = (float)(sum_exp * (double)T_LEN);                  // correct
    }
}

extern "C" void kernel_launch(void* const* d_in, const int* in_sizes, int n_in,
                              void* d_out, int out_size, void* d_ws, size_t ws_size,
                              hipStream_t stream) {
    const float* x     = (const float*)d_in[0];   // [32, 500, 8192] f32
    const int*   Y     = (const int*)  d_in[1];   // [32, 500] int
    const float* B_buf = (const float*)d_in[2];   // [5] f32
    float* out = (float*)d_out;                   // [loss, correct]
    float* cross = (float*)d_ws;                  // 32*32 f32 scratch (4 KB)

    dim3 grid(B_SZ, B_SZ);
    infonce_cross_kernel<<<grid, 256, 0, stream>>>(x, Y, cross);
    infonce_finalize_kernel<<<1, 64, 0, stream>>>(cross, B_buf, out);
}